// Round 6
// baseline (380.318 us; speedup 1.0000x reference)
//
#include <hip/hip_runtime.h>
#include <cstdint>

typedef _Float16 f16;
typedef __attribute__((ext_vector_type(2))) _Float16 f16x2;
typedef __attribute__((ext_vector_type(4))) _Float16 f16x4;
typedef __attribute__((ext_vector_type(8))) _Float16 f16x8;
typedef __attribute__((ext_vector_type(4))) float f32x4;

#if defined(__has_builtin)
# if __has_builtin(__builtin_amdgcn_fdot2)
#  define HAVE_FDOT2 1
# endif
#endif

// ---------------- CSR build ----------------

__global__ void hist_kernel(const int* __restrict__ dst, int* __restrict__ cnt, int E) {
    int e = blockIdx.x * blockDim.x + threadIdx.x;
    if (e < E) atomicAdd(&cnt[dst[e]], 1);
}

__global__ __launch_bounds__(256) void block_scan_kernel(
    const int* __restrict__ cnt, int* __restrict__ rowptr,
    int* __restrict__ partials, int n) {
    __shared__ int lds[256];
    int tid = threadIdx.x;
    int i = blockIdx.x * 256 + tid;
    int v = (i < n) ? cnt[i] : 0;
    lds[tid] = v;
    __syncthreads();
    for (int off = 1; off < 256; off <<= 1) {
        int t = (tid >= off) ? lds[tid - off] : 0;
        __syncthreads();
        lds[tid] += t;
        __syncthreads();
    }
    if (i < n) rowptr[i + 1] = lds[tid];
    if (tid == 255) partials[blockIdx.x] = lds[255];
}

__global__ __launch_bounds__(256) void partial_scan_kernel(int* __restrict__ partials, int nb) {
    __shared__ int lds[256];
    int tid = threadIdx.x;
    int v = (tid < nb) ? partials[tid] : 0;
    lds[tid] = v;
    __syncthreads();
    for (int off = 1; off < 256; off <<= 1) {
        int t = (tid >= off) ? lds[tid - off] : 0;
        __syncthreads();
        lds[tid] += t;
        __syncthreads();
    }
    if (tid < nb) partials[tid] = lds[tid] - v;  // exclusive
}

__global__ __launch_bounds__(256) void add_offsets_kernel(
    int* __restrict__ rowptr, const int* __restrict__ partials, int n) {
    int i = blockIdx.x * 256 + threadIdx.x;
    if (i < n) rowptr[i + 1] += partials[blockIdx.x];
    if (i == 0) rowptr[0] = 0;
}

__global__ void scatter_kernel(const int* __restrict__ src, const int* __restrict__ dst,
                               const int* __restrict__ rowptr, int* __restrict__ cnt,
                               int* __restrict__ src_sorted, int E) {
    int e = blockIdx.x * blockDim.x + threadIdx.x;
    if (e < E) {
        int d = dst[e];
        int p = rowptr[d] + atomicAdd(&cnt[d], 1);
        src_sorted[p] = src[e];
    }
}

// ---------------- weight prep: Wt[c][k] = W[k][c] (fp16), fused q|k|v|s ----------------

__global__ __launch_bounds__(256) void prep_w_kernel(
    const float* __restrict__ Wq, const float* __restrict__ Wk,
    const float* __restrict__ Wv, const float* __restrict__ Ws,
    const float* __restrict__ bq, const float* __restrict__ bk,
    const float* __restrict__ bv, const float* __restrict__ bs,
    f16* __restrict__ Wt, float* __restrict__ bias, int K) {
    int idx = blockIdx.x * 256 + threadIdx.x;
    if (idx < 448) {
        bias[idx] = (idx < 128) ? bq[idx]
                  : (idx < 256) ? bk[idx - 128]
                  : (idx < 384) ? bv[idx - 256]
                  : bs[idx - 384];
    }
    if (idx >= 448 * K) return;
    int c = idx / K, k = idx - c * K;
    float v;
    if (c < 128)      v = Wq[k * 128 + c];
    else if (c < 256) v = Wk[k * 128 + (c - 128)];
    else if (c < 384) v = Wv[k * 128 + (c - 256)];
    else              v = Ws[k * 64 + (c - 384)];
    Wt[(size_t)c * K + k] = (f16)v;
}

// ---------------- fused MFMA GEMM: out[M][448] = X[M][K] @ W[K][448] + b ----------------
// 64 rows x 448 cols per block; X tile staged once, A-fragments in registers;
// W col-tiles double-buffered in LDS (stage ct+1 overlaps MFMA on ct, 1 barrier/iter).
// XOR-swizzle (byte ^= (row&7)<<4) on all tiles.

template <int K, bool F32IN>
__global__ __launch_bounds__(256) void gemm_qkvs_kernel(
    const void* __restrict__ Xv, const f16* __restrict__ Wt,
    const float* __restrict__ bias, f16* __restrict__ out, int M) {
    __shared__ f16 xa[64 * K];
    __shared__ f16 wb[2][64 * K];
    int row0 = blockIdx.x * 64;
    int tid = threadIdx.x;
    constexpr int CPRW = K / 8;

    if (F32IN) {
        const float* X = (const float*)Xv;
        constexpr int CPR = K / 4;
        for (int c = tid; c < 64 * CPR; c += 256) {
            int r = c / CPR, kc = c % CPR;
            int gr = row0 + r;
            float4 v = {0.f, 0.f, 0.f, 0.f};
            if (gr < M) v = *(const float4*)(X + (size_t)gr * K + kc * 4);
            f16x4 hv = {(f16)v.x, (f16)v.y, (f16)v.z, (f16)v.w};
            int off = (r * K + kc * 4) * 2;
            off ^= (r & 7) << 4;
            *(f16x4*)((char*)xa + off) = hv;
        }
    } else {
        const f16* X = (const f16*)Xv;
        for (int c = tid; c < 64 * CPRW; c += 256) {
            int r = c / CPRW, kc = c % CPRW;
            int gr = row0 + r;
            uint4 v = {0, 0, 0, 0};
            if (gr < M) v = *(const uint4*)(X + (size_t)gr * K + kc * 8);
            int off = (r * K + kc * 8) * 2;
            off ^= (r & 7) << 4;
            *(uint4*)((char*)xa + off) = v;
        }
    }
    // stage W tile 0 into wb[0]
    for (int c = tid; c < 64 * CPRW; c += 256) {
        int r = c / CPRW, kc = c % CPRW;
        uint4 v = *(const uint4*)(Wt + (size_t)r * K + kc * 8);
        int off = (r * K + kc * 8) * 2;
        off ^= (r & 7) << 4;
        *(uint4*)((char*)wb[0] + off) = v;
    }
    __syncthreads();

    int lane = tid & 63, wid = tid >> 6;
    int fr = lane & 15, fk = lane >> 4;
    int arow = wid * 16 + fr;
    constexpr int NK = K / 32;
    f16x8 af[NK];
    #pragma unroll
    for (int ks = 0; ks < NK; ++ks) {
        int aoff = (arow * K + ks * 32 + fk * 8) * 2;
        aoff ^= (arow & 7) << 4;
        af[ks] = *(f16x8*)((char*)xa + aoff);
    }

    int orow = row0 + wid * 16 + fk * 4;
    for (int ct = 0; ct < 7; ++ct) {
        // stage next W tile into the other buffer (overlaps with MFMA below)
        if (ct < 6) {
            int col0 = (ct + 1) * 64;
            f16* dstb = wb[(ct + 1) & 1];
            for (int c = tid; c < 64 * CPRW; c += 256) {
                int r = c / CPRW, kc = c % CPRW;
                uint4 v = *(const uint4*)(Wt + (size_t)(col0 + r) * K + kc * 8);
                int off = (r * K + kc * 8) * 2;
                off ^= (r & 7) << 4;
                *(uint4*)((char*)dstb + off) = v;
            }
        }

        const f16* curb = wb[ct & 1];
        f32x4 acc[4] = {};
        #pragma unroll
        for (int ks = 0; ks < NK; ++ks) {
            #pragma unroll
            for (int cf = 0; cf < 4; ++cf) {
                int brow = cf * 16 + fr;
                int boff = (brow * K + ks * 32 + fk * 8) * 2;
                boff ^= (brow & 7) << 4;
                f16x8 bf = *(f16x8*)((char*)curb + boff);
                acc[cf] = __builtin_amdgcn_mfma_f32_16x16x32_f16(af[ks], bf, acc[cf], 0, 0, 0);
            }
        }

        int ocol = ct * 64 + fr;
        #pragma unroll
        for (int cf = 0; cf < 4; ++cf) {
            float b = bias[ocol + cf * 16];
            #pragma unroll
            for (int r = 0; r < 4; ++r) {
                int gr = orow + r;
                if (gr < M) out[(size_t)gr * 448 + ocol + cf * 16] = (f16)(acc[cf][r] + b);
            }
        }
        __syncthreads();
    }
}

// ---------------- fused per-node online-softmax attention ----------------
// One wave per node; lane = (eg:bits3-5, c8:bits0-2); 8 edges/iter, each lane
// owns BOTH heads' 8-channel slices (4x f16x8 loads in flight per lane).
// srcs prefetched one iteration ahead. Deferred-max online softmax.
// Head-mean is lane-local (each lane holds both heads).

__global__ __launch_bounds__(256) void attn_kernel(
    const f16* __restrict__ T,  // [N][448] : q|k|v|s
    const int* __restrict__ rowptr, const int* __restrict__ srcs,
    f16* __restrict__ hout, float* __restrict__ fout, int n, int final_layer) {
    int node = blockIdx.x * 4 + (threadIdx.x >> 6);
    if (node >= n) return;
    int lane = threadIdx.x & 63;
    int c8 = lane & 7, eg = lane >> 3;
    const size_t base = (size_t)node * 448;
    const int co = c8 * 8;

    f16x8 q0 = *(const f16x8*)(T + base + co);
    f16x8 q1 = *(const f16x8*)(T + base + 64 + co);
    float m0 = -__builtin_inff(), m1 = -__builtin_inff();
    float s0 = 0.f, s1 = 0.f;
    float av0[8] = {}, av1[8] = {};

    int beg = rowptr[node], end = rowptr[node + 1];
    if (beg < end) {
        int nsrc = srcs[min(beg + eg, end - 1)];
        for (int i0 = beg; i0 < end; i0 += 8) {
            int i = i0 + eg;
            bool valid = (i < end);
            int sidx = nsrc;
            if (i0 + 8 < end) nsrc = srcs[min(i + 8, end - 1)];

            const f16* p = T + (size_t)sidx * 448 + co;
            f16x8 k0 = *(const f16x8*)(p + 128);
            f16x8 k1 = *(const f16x8*)(p + 192);
            f16x8 v0 = *(const f16x8*)(p + 256);
            f16x8 v1 = *(const f16x8*)(p + 320);

            float d0 = 0.f, d1 = 0.f;
#ifdef HAVE_FDOT2
            #pragma unroll
            for (int j = 0; j < 4; ++j) {
                f16x2 a0 = {q0[2 * j], q0[2 * j + 1]};
                f16x2 b0 = {k0[2 * j], k0[2 * j + 1]};
                d0 = __builtin_amdgcn_fdot2(a0, b0, d0, false);
                f16x2 a1 = {q1[2 * j], q1[2 * j + 1]};
                f16x2 b1 = {k1[2 * j], k1[2 * j + 1]};
                d1 = __builtin_amdgcn_fdot2(a1, b1, d1, false);
            }
#else
            #pragma unroll
            for (int j = 0; j < 8; ++j) {
                d0 += (float)q0[j] * (float)k0[j];
                d1 += (float)q1[j] * (float)k1[j];
            }
#endif
            d0 += __shfl_xor(d0, 1); d1 += __shfl_xor(d1, 1);
            d0 += __shfl_xor(d0, 2); d1 += __shfl_xor(d1, 2);
            d0 += __shfl_xor(d0, 4); d1 += __shfl_xor(d1, 4);
            d0 *= 0.125f; d1 *= 0.125f;  // 1/sqrt(64)
            if (!valid) { d0 = -__builtin_inff(); d1 = -__builtin_inff(); }

            if (__any(d0 > m0 + 6.f || d1 > m1 + 6.f)) {
                float t0 = d0, t1 = d1;
                t0 = fmaxf(t0, __shfl_xor(t0, 8));  t1 = fmaxf(t1, __shfl_xor(t1, 8));
                t0 = fmaxf(t0, __shfl_xor(t0, 16)); t1 = fmaxf(t1, __shfl_xor(t1, 16));
                t0 = fmaxf(t0, __shfl_xor(t0, 32)); t1 = fmaxf(t1, __shfl_xor(t1, 32));
                float nm0 = fmaxf(m0, t0), nm1 = fmaxf(m1, t1);
                float f0 = __expf(m0 - nm0), f1 = __expf(m1 - nm1);
                s0 *= f0; s1 *= f1;
                #pragma unroll
                for (int j = 0; j < 8; ++j) { av0[j] *= f0; av1[j] *= f1; }
                m0 = nm0; m1 = nm1;
            }
            float p0 = __expf(d0 - m0);
            float p1 = __expf(d1 - m1);
            s0 += p0; s1 += p1;
            #pragma unroll
            for (int j = 0; j < 8; ++j) {
                av0[j] += p0 * (float)v0[j];
                av1[j] += p1 * (float)v1[j];
            }
        }
    }

    // reduce partials over the 8 edge-groups (lane bits 3-5)
    s0 += __shfl_xor(s0, 8);  s1 += __shfl_xor(s1, 8);
    s0 += __shfl_xor(s0, 16); s1 += __shfl_xor(s1, 16);
    s0 += __shfl_xor(s0, 32); s1 += __shfl_xor(s1, 32);
    float inv0 = 1.0f / (s0 + 1e-16f), inv1 = 1.0f / (s1 + 1e-16f);
    float r[8];
    #pragma unroll
    for (int j = 0; j < 8; ++j) {
        float a0 = av0[j], a1 = av1[j];
        a0 += __shfl_xor(a0, 8);  a1 += __shfl_xor(a1, 8);
        a0 += __shfl_xor(a0, 16); a1 += __shfl_xor(a1, 16);
        a0 += __shfl_xor(a0, 32); a1 += __shfl_xor(a1, 32);
        r[j] = 0.5f * (a0 * inv0 + a1 * inv1);  // head mean, lane-local
    }

    if (lane < 8) {  // eg==0: 8 lanes x 8 channels = 64 outputs
        f16x8 sk = *(const f16x8*)(T + base + 384 + co);
        #pragma unroll
        for (int j = 0; j < 8; ++j) r[j] = fmaxf(r[j] + (float)sk[j], 0.f);
        if (final_layer) {
            float4* dst4 = (float4*)(fout + (size_t)node * 64 + co);
            dst4[0] = make_float4(r[0], r[1], r[2], r[3]);
            dst4[1] = make_float4(r[4], r[5], r[6], r[7]);
        } else {
            f16x8 o = {(f16)r[0], (f16)r[1], (f16)r[2], (f16)r[3],
                       (f16)r[4], (f16)r[5], (f16)r[6], (f16)r[7]};
            *(f16x8*)(hout + (size_t)node * 64 + co) = o;
        }
    }
}

// ---------------- launch ----------------

extern "C" void kernel_launch(void* const* d_in, const int* in_sizes, int n_in,
                              void* d_out, int out_size, void* d_ws, size_t ws_size,
                              hipStream_t stream) {
    const float* x = (const float*)d_in[0];
    const int* ei  = (const int*)d_in[1];
    const int N = in_sizes[0] / 128;
    const int E = in_sizes[1] / 2;
    const int* src = ei;
    const int* dst = ei + E;

    const float* Wq[3] = {(const float*)d_in[2],  (const float*)d_in[10], (const float*)d_in[18]};
    const float* bq[3] = {(const float*)d_in[3],  (const float*)d_in[11], (const float*)d_in[19]};
    const float* Wk[3] = {(const float*)d_in[4],  (const float*)d_in[12], (const float*)d_in[20]};
    const float* bk[3] = {(const float*)d_in[5],  (const float*)d_in[13], (const float*)d_in[21]};
    const float* Wv[3] = {(const float*)d_in[6],  (const float*)d_in[14], (const float*)d_in[22]};
    const float* bv[3] = {(const float*)d_in[7],  (const float*)d_in[15], (const float*)d_in[23]};
    const float* Wsk[3]= {(const float*)d_in[8],  (const float*)d_in[16], (const float*)d_in[24]};
    const float* bsk[3]= {(const float*)d_in[9],  (const float*)d_in[17], (const float*)d_in[25]};

    char* p = (char*)d_ws;
    int* rowptr   = (int*)p; p += (size_t)(N + 1) * 4;
    int* cnt      = (int*)p; p += (size_t)N * 4;
    int* srcs     = (int*)p; p += (size_t)E * 4;
    int* partials = (int*)p; p += 256 * 4;
    p = (char*)(((uintptr_t)p + 255) & ~(uintptr_t)255);
    f16* Xh   = (f16*)p; p += (size_t)N * 64 * 2;
    f16* QKVS = (f16*)p; p += (size_t)N * 448 * 2;
    f16* Wt0  = (f16*)p; p += (size_t)448 * 128 * 2;
    f16* Wt1  = (f16*)p; p += (size_t)448 * 64 * 2;
    f16* Wt2  = (f16*)p; p += (size_t)448 * 64 * 2;
    float* bias0 = (float*)p; p += 448 * 4;
    float* bias1 = (float*)p; p += 448 * 4;
    float* bias2 = (float*)p; p += 448 * 4;
    if ((size_t)(p - (char*)d_ws) > ws_size) return;

    f16* Wt[3] = {Wt0, Wt1, Wt2};
    float* bias[3] = {bias0, bias1, bias2};

    // all weight prep upfront (independent of CSR chain)
    for (int l = 0; l < 3; ++l) {
        int K = (l == 0) ? 128 : 64;
        prep_w_kernel<<<(448 * K + 255) / 256, 256, 0, stream>>>(
            Wq[l], Wk[l], Wv[l], Wsk[l], bq[l], bk[l], bv[l], bsk[l], Wt[l], bias[l], K);
    }

    int nb = (N + 255) / 256;
    hipMemsetAsync(cnt, 0, (size_t)N * 4, stream);
    hist_kernel<<<(E + 255) / 256, 256, 0, stream>>>(dst, cnt, E);
    block_scan_kernel<<<nb, 256, 0, stream>>>(cnt, rowptr, partials, N);
    partial_scan_kernel<<<1, 256, 0, stream>>>(partials, nb);
    add_offsets_kernel<<<nb, 256, 0, stream>>>(rowptr, partials, N);
    hipMemsetAsync(cnt, 0, (size_t)N * 4, stream);
    scatter_kernel<<<(E + 255) / 256, 256, 0, stream>>>(src, dst, rowptr, cnt, srcs, E);

    int gx = (N + 63) / 64;
    for (int l = 0; l < 3; ++l) {
        if (l == 0)
            gemm_qkvs_kernel<128, true><<<gx, 256, 0, stream>>>(x, Wt[l], bias[l], QKVS, N);
        else
            gemm_qkvs_kernel<64, false><<<gx, 256, 0, stream>>>(Xh, Wt[l], bias[l], QKVS, N);
        attn_kernel<<<(N + 3) / 4, 256, 0, stream>>>(
            QKVS, rowptr, srcs, Xh, (float*)d_out, N, (l == 2) ? 1 : 0);
    }
}

// Round 8
// 358.574 us; speedup vs baseline: 1.0606x; 1.0606x over previous
//
#include <hip/hip_runtime.h>
#include <cstdint>

typedef _Float16 f16;
typedef __attribute__((ext_vector_type(2))) _Float16 f16x2;
typedef __attribute__((ext_vector_type(8))) _Float16 f16x8;
typedef __attribute__((ext_vector_type(4))) float f32x4;

#if defined(__has_builtin)
# if __has_builtin(__builtin_amdgcn_fdot2)
#  define HAVE_FDOT2 1
# endif
#endif

// ---------------- CSR build ----------------

__global__ void hist_kernel(const int* __restrict__ dst, int* __restrict__ cnt, int E) {
    int e = blockIdx.x * blockDim.x + threadIdx.x;
    if (e < E) atomicAdd(&cnt[dst[e]], 1);
}

__global__ __launch_bounds__(256) void block_scan_kernel(
    const int* __restrict__ cnt, int* __restrict__ rowptr,
    int* __restrict__ partials, int n) {
    __shared__ int lds[256];
    int tid = threadIdx.x;
    int i = blockIdx.x * 256 + tid;
    int v = (i < n) ? cnt[i] : 0;
    lds[tid] = v;
    __syncthreads();
    for (int off = 1; off < 256; off <<= 1) {
        int t = (tid >= off) ? lds[tid - off] : 0;
        __syncthreads();
        lds[tid] += t;
        __syncthreads();
    }
    if (i < n) rowptr[i + 1] = lds[tid];
    if (tid == 255) partials[blockIdx.x] = lds[255];
}

__global__ __launch_bounds__(256) void partial_scan_kernel(int* __restrict__ partials, int nb) {
    __shared__ int lds[256];
    int tid = threadIdx.x;
    int v = (tid < nb) ? partials[tid] : 0;
    lds[tid] = v;
    __syncthreads();
    for (int off = 1; off < 256; off <<= 1) {
        int t = (tid >= off) ? lds[tid - off] : 0;
        __syncthreads();
        lds[tid] += t;
        __syncthreads();
    }
    if (tid < nb) partials[tid] = lds[tid] - v;  // exclusive
}

__global__ __launch_bounds__(256) void add_offsets_kernel(
    int* __restrict__ rowptr, const int* __restrict__ partials, int n) {
    int i = blockIdx.x * 256 + threadIdx.x;
    if (i < n) rowptr[i + 1] += partials[blockIdx.x];
    if (i == 0) rowptr[0] = 0;
}

__global__ void scatter_kernel(const int* __restrict__ src, const int* __restrict__ dst,
                               const int* __restrict__ rowptr, int* __restrict__ cnt,
                               int* __restrict__ src_sorted, int E) {
    int e = blockIdx.x * blockDim.x + threadIdx.x;
    if (e < E) {
        int d = dst[e];
        int p = rowptr[d] + atomicAdd(&cnt[d], 1);
        src_sorted[p] = src[e];
    }
}

// ---------------- weight prep: fragment-ordered Wf (fp16), fused q|k|v|s ----------------
// Wf layout: B-fragment block for (ct, cf) spans NK*512 f16; within it,
// offset = ks*512 + fk*128 + fr*8 + j, where lane = fk*16 + fr and
// element = W[k = ks*32 + fk*8 + j][c = ct*64 + cf*16 + fr].
// Each wave's bf load is one contiguous, coalesced 1KB block.

__global__ __launch_bounds__(256) void prep_w_kernel(
    const float* __restrict__ Wq, const float* __restrict__ Wk,
    const float* __restrict__ Wv, const float* __restrict__ Ws,
    const float* __restrict__ bq, const float* __restrict__ bk,
    const float* __restrict__ bv, const float* __restrict__ bs,
    f16* __restrict__ Wf, float* __restrict__ bias, int K) {
    int idx = blockIdx.x * 256 + threadIdx.x;
    if (idx < 448) {
        bias[idx] = (idx < 128) ? bq[idx]
                  : (idx < 256) ? bk[idx - 128]
                  : (idx < 384) ? bv[idx - 256]
                  : bs[idx - 384];
    }
    if (idx >= 448 * K) return;
    int c = idx / K, k = idx - c * K;
    float v;
    if (c < 128)      v = Wq[k * 128 + c];
    else if (c < 256) v = Wk[k * 128 + (c - 128)];
    else if (c < 384) v = Wv[k * 128 + (c - 256)];
    else              v = Ws[k * 64 + (c - 384)];
    int NK = K >> 5;
    int ct = c >> 6, cf = (c >> 4) & 3, fr = c & 15;
    int ks = k >> 5, fk = (k >> 3) & 3, j = k & 7;
    size_t off = ((size_t)(((ct * 4 + cf) * NK + ks) * 4 + fk) * 16 + fr) * 8 + j;
    Wf[off] = (f16)v;
}

// ---------------- LDS-free MFMA GEMM: out[M][448] = X[M][K] @ W + b ----------------
// 256 threads / 4 waves; wave w owns rows [row0 + 16w, +16). A-fragments load
// straight from global X into registers (f32->f16 inline for layer 1); B comes
// from the fragment-ordered Wf table (1KB coalesced wave-loads, L1/L2-resident).
// No LDS, no barriers.

template <int K, bool F32IN>
__global__ __launch_bounds__(256) void gemm_qkvs_kernel(
    const void* __restrict__ Xv, const f16* __restrict__ Wf,
    const float* __restrict__ bias, f16* __restrict__ out, int M) {
    constexpr int NK = K / 32;
    int tid = threadIdx.x;
    int lane = tid & 63, wid = tid >> 6;
    int fr = lane & 15, fk = lane >> 4;
    int arow = blockIdx.x * 64 + wid * 16 + fr;
    int crow = (arow < M) ? arow : (M - 1);

    f16x8 af[NK];
    if (F32IN) {
        const float* X = (const float*)Xv + (size_t)crow * K;
        #pragma unroll
        for (int ks = 0; ks < NK; ++ks) {
            float4 lo = *(const float4*)(X + ks * 32 + fk * 8);
            float4 hi = *(const float4*)(X + ks * 32 + fk * 8 + 4);
            af[ks] = {(f16)lo.x, (f16)lo.y, (f16)lo.z, (f16)lo.w,
                      (f16)hi.x, (f16)hi.y, (f16)hi.z, (f16)hi.w};
        }
    } else {
        const f16* X = (const f16*)Xv + (size_t)crow * K;
        #pragma unroll
        for (int ks = 0; ks < NK; ++ks)
            af[ks] = *(const f16x8*)(X + ks * 32 + fk * 8);
    }

    int orow0 = blockIdx.x * 64 + wid * 16 + fk * 4;
    for (int ct = 0; ct < 7; ++ct) {
        f32x4 acc[4] = {};
        #pragma unroll
        for (int cf = 0; cf < 4; ++cf) {
            // (ct,cf) block stride = NK*512 f16; within: ks*512 + lane*8
            const f16* Wp = Wf + (size_t)(ct * 4 + cf) * NK * 512 + (size_t)lane * 8;
            #pragma unroll
            for (int ks = 0; ks < NK; ++ks) {
                f16x8 bf = *(const f16x8*)(Wp + (size_t)ks * 512);
                acc[cf] = __builtin_amdgcn_mfma_f32_16x16x32_f16(af[ks], bf, acc[cf], 0, 0, 0);
            }
        }
        int ocol = ct * 64 + fr;
        #pragma unroll
        for (int cf = 0; cf < 4; ++cf) {
            float b = bias[ocol + cf * 16];
            #pragma unroll
            for (int r = 0; r < 4; ++r) {
                int gr = orow0 + r;
                if (gr < M) out[(size_t)gr * 448 + ocol + cf * 16] = (f16)(acc[cf][r] + b);
            }
        }
    }
}

// ---------------- fused per-node online-softmax attention ----------------
// One wave per node; lane = (eg:bits3-5, c8:bits0-2); 8 edges/iter, each lane
// owns BOTH heads' 8-channel slices. srcs prefetched one iteration ahead.
// Deferred-max online softmax; head-mean lane-local.

__global__ __launch_bounds__(256) void attn_kernel(
    const f16* __restrict__ T,  // [N][448] : q|k|v|s
    const int* __restrict__ rowptr, const int* __restrict__ srcs,
    f16* __restrict__ hout, float* __restrict__ fout, int n, int final_layer) {
    int node = blockIdx.x * 4 + (threadIdx.x >> 6);
    if (node >= n) return;
    int lane = threadIdx.x & 63;
    int c8 = lane & 7, eg = lane >> 3;
    const size_t base = (size_t)node * 448;
    const int co = c8 * 8;

    f16x8 q0 = *(const f16x8*)(T + base + co);
    f16x8 q1 = *(const f16x8*)(T + base + 64 + co);
    float m0 = -__builtin_inff(), m1 = -__builtin_inff();
    float s0 = 0.f, s1 = 0.f;
    float av0[8] = {}, av1[8] = {};

    int beg = rowptr[node], end = rowptr[node + 1];
    if (beg < end) {
        int nsrc = srcs[min(beg + eg, end - 1)];
        for (int i0 = beg; i0 < end; i0 += 8) {
            int i = i0 + eg;
            bool valid = (i < end);
            int sidx = nsrc;
            if (i0 + 8 < end) nsrc = srcs[min(i + 8, end - 1)];

            const f16* p = T + (size_t)sidx * 448 + co;
            f16x8 k0 = *(const f16x8*)(p + 128);
            f16x8 k1 = *(const f16x8*)(p + 192);
            f16x8 v0 = *(const f16x8*)(p + 256);
            f16x8 v1 = *(const f16x8*)(p + 320);

            float d0 = 0.f, d1 = 0.f;
#ifdef HAVE_FDOT2
            #pragma unroll
            for (int j = 0; j < 4; ++j) {
                f16x2 a0 = {q0[2 * j], q0[2 * j + 1]};
                f16x2 b0 = {k0[2 * j], k0[2 * j + 1]};
                d0 = __builtin_amdgcn_fdot2(a0, b0, d0, false);
                f16x2 a1 = {q1[2 * j], q1[2 * j + 1]};
                f16x2 b1 = {k1[2 * j], k1[2 * j + 1]};
                d1 = __builtin_amdgcn_fdot2(a1, b1, d1, false);
            }
#else
            #pragma unroll
            for (int j = 0; j < 8; ++j) {
                d0 += (float)q0[j] * (float)k0[j];
                d1 += (float)q1[j] * (float)k1[j];
            }
#endif
            d0 += __shfl_xor(d0, 1); d1 += __shfl_xor(d1, 1);
            d0 += __shfl_xor(d0, 2); d1 += __shfl_xor(d1, 2);
            d0 += __shfl_xor(d0, 4); d1 += __shfl_xor(d1, 4);
            d0 *= 0.125f; d1 *= 0.125f;  // 1/sqrt(64)
            if (!valid) { d0 = -__builtin_inff(); d1 = -__builtin_inff(); }

            if (__any(d0 > m0 + 6.f || d1 > m1 + 6.f)) {
                float t0 = d0, t1 = d1;
                t0 = fmaxf(t0, __shfl_xor(t0, 8));  t1 = fmaxf(t1, __shfl_xor(t1, 8));
                t0 = fmaxf(t0, __shfl_xor(t0, 16)); t1 = fmaxf(t1, __shfl_xor(t1, 16));
                t0 = fmaxf(t0, __shfl_xor(t0, 32)); t1 = fmaxf(t1, __shfl_xor(t1, 32));
                float nm0 = fmaxf(m0, t0), nm1 = fmaxf(m1, t1);
                float f0 = __expf(m0 - nm0), f1 = __expf(m1 - nm1);
                s0 *= f0; s1 *= f1;
                #pragma unroll
                for (int j = 0; j < 8; ++j) { av0[j] *= f0; av1[j] *= f1; }
                m0 = nm0; m1 = nm1;
            }
            float p0 = __expf(d0 - m0);
            float p1 = __expf(d1 - m1);
            s0 += p0; s1 += p1;
            #pragma unroll
            for (int j = 0; j < 8; ++j) {
                av0[j] += p0 * (float)v0[j];
                av1[j] += p1 * (float)v1[j];
            }
        }
    }

    // reduce partials over the 8 edge-groups (lane bits 3-5)
    s0 += __shfl_xor(s0, 8);  s1 += __shfl_xor(s1, 8);
    s0 += __shfl_xor(s0, 16); s1 += __shfl_xor(s1, 16);
    s0 += __shfl_xor(s0, 32); s1 += __shfl_xor(s1, 32);
    float inv0 = 1.0f / (s0 + 1e-16f), inv1 = 1.0f / (s1 + 1e-16f);
    float r[8];
    #pragma unroll
    for (int j = 0; j < 8; ++j) {
        float a0 = av0[j], a1 = av1[j];
        a0 += __shfl_xor(a0, 8);  a1 += __shfl_xor(a1, 8);
        a0 += __shfl_xor(a0, 16); a1 += __shfl_xor(a1, 16);
        a0 += __shfl_xor(a0, 32); a1 += __shfl_xor(a1, 32);
        r[j] = 0.5f * (a0 * inv0 + a1 * inv1);  // head mean, lane-local
    }

    if (lane < 8) {  // eg==0: 8 lanes x 8 channels = 64 outputs
        f16x8 sk = *(const f16x8*)(T + base + 384 + co);
        #pragma unroll
        for (int j = 0; j < 8; ++j) r[j] = fmaxf(r[j] + (float)sk[j], 0.f);
        if (final_layer) {
            float4* dst4 = (float4*)(fout + (size_t)node * 64 + co);
            dst4[0] = make_float4(r[0], r[1], r[2], r[3]);
            dst4[1] = make_float4(r[4], r[5], r[6], r[7]);
        } else {
            f16x8 o = {(f16)r[0], (f16)r[1], (f16)r[2], (f16)r[3],
                       (f16)r[4], (f16)r[5], (f16)r[6], (f16)r[7]};
            *(f16x8*)(hout + (size_t)node * 64 + co) = o;
        }
    }
}

// ---------------- launch ----------------

extern "C" void kernel_launch(void* const* d_in, const int* in_sizes, int n_in,
                              void* d_out, int out_size, void* d_ws, size_t ws_size,
                              hipStream_t stream) {
    const float* x = (const float*)d_in[0];
    const int* ei  = (const int*)d_in[1];
    const int N = in_sizes[0] / 128;
    const int E = in_sizes[1] / 2;
    const int* src = ei;
    const int* dst = ei + E;

    const float* Wq[3] = {(const float*)d_in[2],  (const float*)d_in[10], (const float*)d_in[18]};
    const float* bq[3] = {(const float*)d_in[3],  (const float*)d_in[11], (const float*)d_in[19]};
    const float* Wk[3] = {(const float*)d_in[4],  (const float*)d_in[12], (const float*)d_in[20]};
    const float* bk[3] = {(const float*)d_in[5],  (const float*)d_in[13], (const float*)d_in[21]};
    const float* Wv[3] = {(const float*)d_in[6],  (const float*)d_in[14], (const float*)d_in[22]};
    const float* bv[3] = {(const float*)d_in[7],  (const float*)d_in[15], (const float*)d_in[23]};
    const float* Wsk[3]= {(const float*)d_in[8],  (const float*)d_in[16], (const float*)d_in[24]};
    const float* bsk[3]= {(const float*)d_in[9],  (const float*)d_in[17], (const float*)d_in[25]};

    char* p = (char*)d_ws;
    int* rowptr   = (int*)p; p += (size_t)(N + 1) * 4;
    int* cnt      = (int*)p; p += (size_t)N * 4;
    int* srcs     = (int*)p; p += (size_t)E * 4;
    int* partials = (int*)p; p += 256 * 4;
    p = (char*)(((uintptr_t)p + 255) & ~(uintptr_t)255);
    f16* Xh   = (f16*)p; p += (size_t)N * 64 * 2;
    f16* QKVS = (f16*)p; p += (size_t)N * 448 * 2;
    f16* Wt0  = (f16*)p; p += (size_t)448 * 128 * 2;
    f16* Wt1  = (f16*)p; p += (size_t)448 * 64 * 2;
    f16* Wt2  = (f16*)p; p += (size_t)448 * 64 * 2;
    float* bias0 = (float*)p; p += 448 * 4;
    float* bias1 = (float*)p; p += 448 * 4;
    float* bias2 = (float*)p; p += 448 * 4;
    if ((size_t)(p - (char*)d_ws) > ws_size) return;

    f16* Wt[3] = {Wt0, Wt1, Wt2};
    float* bias[3] = {bias0, bias1, bias2};

    // all weight prep upfront (independent of CSR chain)
    for (int l = 0; l < 3; ++l) {
        int K = (l == 0) ? 128 : 64;
        prep_w_kernel<<<(448 * K + 255) / 256, 256, 0, stream>>>(
            Wq[l], Wk[l], Wv[l], Wsk[l], bq[l], bk[l], bv[l], bsk[l], Wt[l], bias[l], K);
    }

    int nb = (N + 255) / 256;
    hipMemsetAsync(cnt, 0, (size_t)N * 4, stream);
    hist_kernel<<<(E + 255) / 256, 256, 0, stream>>>(dst, cnt, E);
    block_scan_kernel<<<nb, 256, 0, stream>>>(cnt, rowptr, partials, N);
    partial_scan_kernel<<<1, 256, 0, stream>>>(partials, nb);
    add_offsets_kernel<<<nb, 256, 0, stream>>>(rowptr, partials, N);
    hipMemsetAsync(cnt, 0, (size_t)N * 4, stream);
    scatter_kernel<<<(E + 255) / 256, 256, 0, stream>>>(src, dst, rowptr, cnt, srcs, E);

    int gx = (N + 63) / 64;
    for (int l = 0; l < 3; ++l) {
        if (l == 0)
            gemm_qkvs_kernel<128, true><<<gx, 256, 0, stream>>>(x, Wt[l], bias[l], QKVS, N);
        else
            gemm_qkvs_kernel<64, false><<<gx, 256, 0, stream>>>(Xh, Wt[l], bias[l], QKVS, N);
        attn_kernel<<<(N + 3) / 4, 256, 0, stream>>>(
            QKVS, rowptr, srcs, Xh, (float*)d_out, N, (l == 2) ? 1 : 0);
    }
}